// Round 1
// baseline (827.874 us; speedup 1.0000x reference)
//
#include <hip/hip_runtime.h>
#include <hip/hip_bf16.h>

#define N_NODES 50000
#define N_EDGES 800000
#define NF 64   // IN_F == OUT_F == 64

// -------------------- kernel 1: support = x @ W --------------------
// One wave (64 lanes) per row: lane f computes support[row][f].
// W (64x64 = 16 KB) staged in LDS; lane accesses wlds[k*64+f] are
// stride-1 across lanes -> 2 lanes/bank -> conflict-free on CDNA4.
__global__ __launch_bounds__(256) void gemm_xw(
    const float* __restrict__ x, const float* __restrict__ w,
    float* __restrict__ support) {
  __shared__ float wlds[NF * NF];
  for (int i = threadIdx.x; i < NF * NF; i += 256) wlds[i] = w[i];
  __syncthreads();

  const int lane = threadIdx.x & 63;
  const int wave = threadIdx.x >> 6;
  const int waves_per_blk = 256 >> 6;  // 4

  for (int row = blockIdx.x * waves_per_blk + wave; row < N_NODES;
       row += gridDim.x * waves_per_blk) {
    const float* xr = x + (size_t)row * NF;
    float acc = 0.f;
#pragma unroll
    for (int k = 0; k < NF; ++k) {
      acc = fmaf(xr[k], wlds[k * NF + lane], acc);  // xr[k] wave-uniform broadcast
    }
    support[(size_t)row * NF + lane] = acc;
  }
}

// -------------------- kernel 2: out[i] = bias[i % 64] --------------------
__global__ __launch_bounds__(256) void init_bias(
    float* __restrict__ out, const float* __restrict__ bias) {
  const int total4 = N_NODES * NF / 4;  // float4 elements
  float4 b4[16];
#pragma unroll
  for (int i = 0; i < 16; ++i)
    b4[i] = reinterpret_cast<const float4*>(bias)[i];
  float4* out4 = reinterpret_cast<float4*>(out);
  for (int i = blockIdx.x * 256 + threadIdx.x; i < total4;
       i += gridDim.x * 256) {
    out4[i] = b4[i & 15];
  }
}

// -------------------- kernel 3: edge scatter --------------------
// 16 threads per edge; each loads float4 of support[col] and does 4 HW
// fp32 atomics into out[row]. unsafeAtomicAdd -> global_atomic_add_f32.
__global__ __launch_bounds__(256) void spmm_scatter(
    const float* __restrict__ support, const int* __restrict__ erow,
    const int* __restrict__ ecol, const float* __restrict__ eval,
    float* __restrict__ out) {
  const long long tid = (long long)blockIdx.x * 256 + threadIdx.x;
  const int e = (int)(tid >> 4);
  if (e >= N_EDGES) return;
  const int p = (int)(tid & 15);

  const int r = erow[e];
  const int c = ecol[e];
  const float v = eval[e];

  const float4 s =
      *reinterpret_cast<const float4*>(support + (size_t)c * NF + p * 4);
  float* o = out + (size_t)r * NF + p * 4;
  unsafeAtomicAdd(o + 0, v * s.x);
  unsafeAtomicAdd(o + 1, v * s.y);
  unsafeAtomicAdd(o + 2, v * s.z);
  unsafeAtomicAdd(o + 3, v * s.w);
}

// -------------------- launch --------------------
extern "C" void kernel_launch(void* const* d_in, const int* in_sizes, int n_in,
                              void* d_out, int out_size, void* d_ws,
                              size_t ws_size, hipStream_t stream) {
  const float* x = (const float*)d_in[0];
  const int* erow = (const int*)d_in[1];
  const int* ecol = (const int*)d_in[2];
  const float* eval = (const float*)d_in[3];
  const float* w = (const float*)d_in[4];
  const float* bias = (const float*)d_in[5];
  float* out = (float*)d_out;

  float* support = (float*)d_ws;  // 50000*64*4 = 12.8 MB scratch

  // 1) support = x @ W   (50000 rows, 4 rows/block)
  gemm_xw<<<(N_NODES + 3) / 4, 256, 0, stream>>>(x, w, support);

  // 2) out = bias (broadcast); must fully overwrite poisoned d_out
  init_bias<<<1024, 256, 0, stream>>>(out, bias);

  // 3) scatter: 800000 edges * 16 threads = 12.8M threads
  const long long total = (long long)N_EDGES * 16;
  spmm_scatter<<<(int)((total + 255) / 256), 256, 0, stream>>>(
      support, erow, ecol, eval, out);
}

// Round 2
// 219.047 us; speedup vs baseline: 3.7794x; 3.7794x over previous
//
#include <hip/hip_runtime.h>
#include <hip/hip_bf16.h>

#define N_NODES 50000
#define N_EDGES 800000
#define NF 64   // IN_F == OUT_F == 64

// -------------------- kernel 1: support = x @ W --------------------
// One wave per row. Lane f holds W[:,f] in 64 VGPRs (loaded once per wave,
// coalesced). x row is read through scalar loads (row forced wave-uniform via
// readfirstlane) -> s_load_dwordx16 batches, broadcast to FMAs. 4 accumulators
// break the dependent-FMA chain.
__global__ __launch_bounds__(256) void gemm_xw(
    const float* __restrict__ x, const float* __restrict__ w,
    float* __restrict__ support) {
  const int lane = threadIdx.x & 63;
  const int wave = threadIdx.x >> 6;

  float wcol[NF];
#pragma unroll
  for (int k = 0; k < NF; ++k) wcol[k] = w[k * NF + lane];

  const int nwaves = gridDim.x * 4;
  for (int row = blockIdx.x * 4 + wave; row < N_NODES; row += nwaves) {
    const int row_u = __builtin_amdgcn_readfirstlane(row);
    const float* xr = x + (size_t)row_u * NF;
    float a0 = 0.f, a1 = 0.f, a2 = 0.f, a3 = 0.f;
#pragma unroll
    for (int k = 0; k < NF; k += 4) {
      a0 = fmaf(xr[k + 0], wcol[k + 0], a0);
      a1 = fmaf(xr[k + 1], wcol[k + 1], a1);
      a2 = fmaf(xr[k + 2], wcol[k + 2], a2);
      a3 = fmaf(xr[k + 3], wcol[k + 3], a3);
    }
    support[(size_t)row_u * NF + lane] = (a0 + a1) + (a2 + a3);
  }
}

// -------------------- kernel 2: histogram of rows --------------------
__global__ __launch_bounds__(256) void hist_rows(const int* __restrict__ erow,
                                                 int* __restrict__ counts) {
  const int e = blockIdx.x * 256 + threadIdx.x;
  if (e < N_EDGES) atomicAdd(&counts[erow[e]], 1);
}

// -------------------- kernel 3: exclusive scan of counts --------------------
// Single block, 1024 threads, 8 elements/thread -> 8192/iter, 7 iterations.
// Wave-level shfl scan + cross-wave LDS scan + running carry.
__global__ __launch_bounds__(1024) void scan_counts(
    const int* __restrict__ counts, int* __restrict__ row_start,
    int* __restrict__ pos) {
  __shared__ int wsum[16];
  __shared__ int carry_s;
  const int tid = threadIdx.x;
  const int lane = tid & 63;
  const int wv = tid >> 6;
  if (tid == 0) carry_s = 0;
  __syncthreads();

  for (int base = 0; base < N_NODES; base += 8192) {
    const int idx0 = base + tid * 8;
    int v[8];
#pragma unroll
    for (int j = 0; j < 8; ++j) {
      const int idx = idx0 + j;
      v[j] = (idx < N_NODES) ? counts[idx] : 0;
    }
    // thread-local inclusive scan
#pragma unroll
    for (int j = 1; j < 8; ++j) v[j] += v[j - 1];
    const int tsum = v[7];

    // wave inclusive scan of per-thread sums
    int scan = tsum;
#pragma unroll
    for (int off = 1; off < 64; off <<= 1) {
      const int up = __shfl_up(scan, off, 64);
      if (lane >= off) scan += up;
    }
    if (lane == 63) wsum[wv] = scan;
    __syncthreads();

    // exclusive cross-wave offset (16 values; every thread sums — cheap)
    int woff = 0;
#pragma unroll
    for (int k = 0; k < 16; ++k) woff += (k < wv) ? wsum[k] : 0;

    const int excl_thread = (scan - tsum) + woff + carry_s;
    int outv[8];
    outv[0] = excl_thread;
#pragma unroll
    for (int j = 1; j < 8; ++j) outv[j] = excl_thread + v[j - 1];
#pragma unroll
    for (int j = 0; j < 8; ++j) {
      const int idx = idx0 + j;
      if (idx < N_NODES) {
        row_start[idx] = outv[j];
        pos[idx] = outv[j];
      }
    }
    __syncthreads();                        // everyone done reading carry_s/wsum
    if (tid == 1023) carry_s += woff + scan;  // tile total
    __syncthreads();
  }
  if (tid == 0) row_start[N_NODES] = N_EDGES;
}

// -------------------- kernel 4: place edges into CSR buckets --------------------
__global__ __launch_bounds__(256) void scatter_edges(
    const int* __restrict__ erow, const int* __restrict__ ecol,
    const float* __restrict__ eval, int* __restrict__ pos,
    int2* __restrict__ packed) {
  const int e = blockIdx.x * 256 + threadIdx.x;
  if (e >= N_EDGES) return;
  const int r = erow[e];
  const int p = atomicAdd(&pos[r], 1);
  packed[p] = make_int2(ecol[e], __float_as_int(eval[e]));
}

// -------------------- kernel 5: CSR SpMM + bias (no atomics) --------------------
// One wave per row; lane f accumulates out[row][f]. 4-way unroll keeps 4
// gathers of support rows in flight.
__global__ __launch_bounds__(256) void spmm_csr(
    const float* __restrict__ support, const int* __restrict__ row_start,
    const int2* __restrict__ packed, const float* __restrict__ bias,
    float* __restrict__ out) {
  const int lane = threadIdx.x & 63;
  const int wave = threadIdx.x >> 6;
  int row = blockIdx.x * 4 + wave;
  if (row >= N_NODES) return;
  row = __builtin_amdgcn_readfirstlane(row);

  int s = __builtin_amdgcn_readfirstlane(row_start[row]);
  int e = __builtin_amdgcn_readfirstlane(row_start[row + 1]);

  float a0 = 0.f, a1 = 0.f, a2 = 0.f, a3 = 0.f;
  int i = s;
  for (; i + 4 <= e; i += 4) {
    const int2 p0 = packed[i + 0];
    const int2 p1 = packed[i + 1];
    const int2 p2 = packed[i + 2];
    const int2 p3 = packed[i + 3];
    a0 = fmaf(__int_as_float(p0.y), support[(size_t)p0.x * NF + lane], a0);
    a1 = fmaf(__int_as_float(p1.y), support[(size_t)p1.x * NF + lane], a1);
    a2 = fmaf(__int_as_float(p2.y), support[(size_t)p2.x * NF + lane], a2);
    a3 = fmaf(__int_as_float(p3.y), support[(size_t)p3.x * NF + lane], a3);
  }
  for (; i < e; ++i) {
    const int2 p0 = packed[i];
    a0 = fmaf(__int_as_float(p0.y), support[(size_t)p0.x * NF + lane], a0);
  }
  out[(size_t)row * NF + lane] = ((a0 + a1) + (a2 + a3)) + bias[lane];
}

// -------------------- launch --------------------
extern "C" void kernel_launch(void* const* d_in, const int* in_sizes, int n_in,
                              void* d_out, int out_size, void* d_ws,
                              size_t ws_size, hipStream_t stream) {
  const float* x = (const float*)d_in[0];
  const int* erow = (const int*)d_in[1];
  const int* ecol = (const int*)d_in[2];
  const float* eval = (const float*)d_in[3];
  const float* w = (const float*)d_in[4];
  const float* bias = (const float*)d_in[5];
  float* out = (float*)d_out;

  // workspace layout (all 16B-aligned)
  char* ws = (char*)d_ws;
  float* support = (float*)(ws);                       // 12,800,000 B
  int* counts = (int*)(ws + 12800000);                 //    200,000 B
  int* row_start = (int*)(ws + 13000000);              //    200,016 B (50001)
  int* pos = (int*)(ws + 13200016);                    //    200,000 B
  int2* packed = (int2*)(ws + 13400016);               //  6,400,000 B
  // total: 19,800,016 B

  hipMemsetAsync(counts, 0, N_NODES * sizeof(int), stream);

  gemm_xw<<<1024, 256, 0, stream>>>(x, w, support);
  hist_rows<<<(N_EDGES + 255) / 256, 256, 0, stream>>>(erow, counts);
  scan_counts<<<1, 1024, 0, stream>>>(counts, row_start, pos);
  scatter_edges<<<(N_EDGES + 255) / 256, 256, 0, stream>>>(erow, ecol, eval,
                                                           pos, packed);
  spmm_csr<<<(N_NODES + 3) / 4, 256, 0, stream>>>(support, row_start, packed,
                                                  bias, out);
}

// Round 3
// 172.925 us; speedup vs baseline: 4.7875x; 1.2667x over previous
//
#include <hip/hip_runtime.h>
#include <hip/hip_bf16.h>

#define N_NODES 50000
#define N_EDGES 800000
#define NF 64           // IN_F == OUT_F == 64
#define BUCK_SHIFT 7
#define BUCK_SIZE 128   // rows per coarse bucket
#define NBUK ((N_NODES + BUCK_SIZE - 1) / BUCK_SIZE)  // 391
#define CHUNK 4096      // edges per bin_scatter block

// -------------------- kernel 1: support = bf16(x @ W) --------------------
// One wave per row; lane f holds W[:,f] in 64 VGPRs. x row reads are
// wave-uniform -> scalar loads. bf16 store halves writeback + later gather BW.
__global__ __launch_bounds__(256) void gemm_xw(
    const float* __restrict__ x, const float* __restrict__ w,
    __hip_bfloat16* __restrict__ support) {
  const int lane = threadIdx.x & 63;
  const int wave = threadIdx.x >> 6;

  float wcol[NF];
#pragma unroll
  for (int k = 0; k < NF; ++k) wcol[k] = w[k * NF + lane];

  const int nwaves = gridDim.x * 4;
  for (int row = blockIdx.x * 4 + wave; row < N_NODES; row += nwaves) {
    const int row_u = __builtin_amdgcn_readfirstlane(row);
    const float* xr = x + (size_t)row_u * NF;
    float a0 = 0.f, a1 = 0.f, a2 = 0.f, a3 = 0.f;
#pragma unroll
    for (int k = 0; k < NF; k += 4) {
      a0 = fmaf(xr[k + 0], wcol[k + 0], a0);
      a1 = fmaf(xr[k + 1], wcol[k + 1], a1);
      a2 = fmaf(xr[k + 2], wcol[k + 2], a2);
      a3 = fmaf(xr[k + 3], wcol[k + 3], a3);
    }
    support[(size_t)row_u * NF + lane] = __float2bfloat16((a0 + a1) + (a2 + a3));
  }
}

// -------------------- kernel 2: coarse histogram (391 buckets) --------------------
__global__ __launch_bounds__(256) void coarse_hist(const int* __restrict__ erow,
                                                   int* __restrict__ bcnt) {
  __shared__ int hist[NBUK];
  for (int t = threadIdx.x; t < NBUK; t += 256) hist[t] = 0;
  __syncthreads();
  for (int e = blockIdx.x * 256 + threadIdx.x; e < N_EDGES;
       e += gridDim.x * 256)
    atomicAdd(&hist[erow[e] >> BUCK_SHIFT], 1);
  __syncthreads();
  for (int t = threadIdx.x; t < NBUK; t += 256)
    if (hist[t]) atomicAdd(&bcnt[t], hist[t]);
}

// -------------------- kernel 3: scan 391 bucket counts --------------------
__global__ __launch_bounds__(512) void scan_coarse(
    const int* __restrict__ bcnt, int* __restrict__ bstart,
    int* __restrict__ cursor, int* __restrict__ row_start) {
  __shared__ int wsum[8];
  const int t = threadIdx.x;
  const int lane = t & 63;
  const int wv = t >> 6;
  const int v = (t < NBUK) ? bcnt[t] : 0;
  int scan = v;
#pragma unroll
  for (int off = 1; off < 64; off <<= 1) {
    const int up = __shfl_up(scan, off, 64);
    if (lane >= off) scan += up;
  }
  if (lane == 63) wsum[wv] = scan;
  __syncthreads();
  int woff = 0;
#pragma unroll
  for (int k = 0; k < 8; ++k) woff += (k < wv) ? wsum[k] : 0;
  const int excl = scan - v + woff;
  if (t < NBUK) {
    bstart[t] = excl;
    cursor[t] = excl;
  }
  if (t == 0) {
    bstart[NBUK] = N_EDGES;
    row_start[N_NODES] = N_EDGES;
  }
}

// -------------------- kernel 4: bin edges into coarse buckets --------------------
// Each block handles CHUNK contiguous edges; reserves one contiguous run per
// bucket via a single global atomic, then writes runs (~10 edges each) ->
// mostly line-merged writes instead of isolated 8-B stores.
__global__ __launch_bounds__(256) void bin_scatter(
    const int* __restrict__ erow, const int* __restrict__ ecol,
    const float* __restrict__ eval, int* __restrict__ cursor,
    int2* __restrict__ stage1) {
  __shared__ int hist[NBUK];
  __shared__ int base[NBUK];
  __shared__ int lcur[NBUK];
  for (int t = threadIdx.x; t < NBUK; t += 256) hist[t] = 0;
  __syncthreads();
  const int e0 = blockIdx.x * CHUNK;
  const int e1 = min(e0 + CHUNK, N_EDGES);
  for (int e = e0 + threadIdx.x; e < e1; e += 256)
    atomicAdd(&hist[erow[e] >> BUCK_SHIFT], 1);
  __syncthreads();
  for (int t = threadIdx.x; t < NBUK; t += 256) {
    const int c = hist[t];
    base[t] = c ? atomicAdd(&cursor[t], c) : 0;
    lcur[t] = 0;
  }
  __syncthreads();
  for (int e = e0 + threadIdx.x; e < e1; e += 256) {
    const int r = erow[e];
    const int b = r >> BUCK_SHIFT;
    const int ofs = atomicAdd(&lcur[b], 1);
    // meta: local row (7b) in bits 16.., col (<50000 < 2^16) in low 16
    stage1[base[b] + ofs] =
        make_int2(((r & (BUCK_SIZE - 1)) << 16) | ecol[e],
                  __float_as_int(eval[e]));
  }
}

// -------------------- kernel 5: per-bucket exact CSR build --------------------
// One block per bucket: count per-row in LDS, scan 128 rows (wave 0), place
// edges. All writes to this bucket's region come from ONE block -> one L2 ->
// full-line writebacks.
__global__ __launch_bounds__(256) void build_csr(
    const int2* __restrict__ stage1, const int* __restrict__ bstart,
    int* __restrict__ row_start, int2* __restrict__ packed) {
  __shared__ int rcnt[BUCK_SIZE];
  __shared__ int rexcl[BUCK_SIZE];
  __shared__ int rcur[BUCK_SIZE];
  const int b = blockIdx.x;
  const int row0 = b << BUCK_SHIFT;
  const int nrows = min(BUCK_SIZE, N_NODES - row0);
  const int s = bstart[b];
  const int e = bstart[b + 1];
  const int tid = threadIdx.x;

  if (tid < BUCK_SIZE) rcnt[tid] = 0;
  __syncthreads();
  for (int i = s + tid; i < e; i += 256) atomicAdd(&rcnt[stage1[i].x >> 16], 1);
  __syncthreads();

  if (tid < 64) {
    const int lane = tid;
    const int a = rcnt[lane];
    const int c = rcnt[64 + lane];
    int sa = a, sc = c;
#pragma unroll
    for (int off = 1; off < 64; off <<= 1) {
      const int ua = __shfl_up(sa, off, 64);
      const int uc = __shfl_up(sc, off, 64);
      if (lane >= off) {
        sa += ua;
        sc += uc;
      }
    }
    const int tot_a = __shfl(sa, 63, 64);
    rexcl[lane] = sa - a;
    rexcl[64 + lane] = tot_a + sc - c;
  }
  __syncthreads();
  if (tid < BUCK_SIZE) rcur[tid] = rexcl[tid];
  if (tid < nrows) row_start[row0 + tid] = s + rexcl[tid];
  __syncthreads();

  for (int i = s + tid; i < e; i += 256) {
    const int2 ev = stage1[i];
    const int rl = ev.x >> 16;
    const int col = ev.x & 0xFFFF;
    const int ofs = atomicAdd(&rcur[rl], 1);
    packed[s + ofs] = make_int2(col, ev.y);
  }
}

// -------------------- kernel 6: CSR SpMM + bias (no atomics) --------------------
__global__ __launch_bounds__(256) void spmm_csr(
    const __hip_bfloat16* __restrict__ support,
    const int* __restrict__ row_start, const int2* __restrict__ packed,
    const float* __restrict__ bias, float* __restrict__ out) {
  const int lane = threadIdx.x & 63;
  const int wave = threadIdx.x >> 6;
  int row = blockIdx.x * 4 + wave;
  if (row >= N_NODES) return;
  row = __builtin_amdgcn_readfirstlane(row);

  const int s = __builtin_amdgcn_readfirstlane(row_start[row]);
  const int e = __builtin_amdgcn_readfirstlane(row_start[row + 1]);

  float a0 = 0.f, a1 = 0.f, a2 = 0.f, a3 = 0.f;
  int i = s;
  for (; i + 4 <= e; i += 4) {
    const int2 p0 = packed[i + 0];
    const int2 p1 = packed[i + 1];
    const int2 p2 = packed[i + 2];
    const int2 p3 = packed[i + 3];
    const float s0 = __bfloat162float(support[(size_t)p0.x * NF + lane]);
    const float s1 = __bfloat162float(support[(size_t)p1.x * NF + lane]);
    const float s2 = __bfloat162float(support[(size_t)p2.x * NF + lane]);
    const float s3 = __bfloat162float(support[(size_t)p3.x * NF + lane]);
    a0 = fmaf(__int_as_float(p0.y), s0, a0);
    a1 = fmaf(__int_as_float(p1.y), s1, a1);
    a2 = fmaf(__int_as_float(p2.y), s2, a2);
    a3 = fmaf(__int_as_float(p3.y), s3, a3);
  }
  for (; i < e; ++i) {
    const int2 p0 = packed[i];
    a0 = fmaf(__int_as_float(p0.y),
              __bfloat162float(support[(size_t)p0.x * NF + lane]), a0);
  }
  out[(size_t)row * NF + lane] = ((a0 + a1) + (a2 + a3)) + bias[lane];
}

// -------------------- launch --------------------
extern "C" void kernel_launch(void* const* d_in, const int* in_sizes, int n_in,
                              void* d_out, int out_size, void* d_ws,
                              size_t ws_size, hipStream_t stream) {
  const float* x = (const float*)d_in[0];
  const int* erow = (const int*)d_in[1];
  const int* ecol = (const int*)d_in[2];
  const float* eval = (const float*)d_in[3];
  const float* w = (const float*)d_in[4];
  const float* bias = (const float*)d_in[5];
  float* out = (float*)d_out;

  // workspace layout (16B-aligned)
  char* ws = (char*)d_ws;
  __hip_bfloat16* support = (__hip_bfloat16*)(ws);   //  6,400,000 B
  int2* stage1 = (int2*)(ws + 6400000);              //  6,400,000 B
  int2* packed = (int2*)(ws + 12800000);             //  6,400,000 B
  int* row_start = (int*)(ws + 19200000);            //    200,016 B (50001)
  int* bcnt = (int*)(ws + 19400016);                 //      1,568 B (391)
  int* bstart = (int*)(ws + 19401584);               //      1,568 B (392)
  int* cursor = (int*)(ws + 19403152);               //      1,568 B (391)
  // total ~19.40 MB

  hipMemsetAsync(bcnt, 0, NBUK * sizeof(int), stream);

  gemm_xw<<<1024, 256, 0, stream>>>(x, w, support);
  coarse_hist<<<784, 256, 0, stream>>>(erow, bcnt);
  scan_coarse<<<1, 512, 0, stream>>>(bcnt, bstart, cursor, row_start);
  bin_scatter<<<(N_EDGES + CHUNK - 1) / CHUNK, 256, 0, stream>>>(
      erow, ecol, eval, cursor, stage1);
  build_csr<<<NBUK, 256, 0, stream>>>(stage1, bstart, row_start, packed);
  spmm_csr<<<(N_NODES + 3) / 4, 256, 0, stream>>>(support, row_start, packed,
                                                  bias, out);
}